// Round 3
// baseline (9462.743 us; speedup 1.0000x reference)
//
#include <hip/hip_runtime.h>
#include <stdint.h>
#include <stddef.h>

typedef _Float16 f16;
typedef _Float16 half8 __attribute__((ext_vector_type(8)));
typedef float floatx4 __attribute__((ext_vector_type(4)));
typedef unsigned long long u64;

#define MFMA(a,b,c) __builtin_amdgcn_mfma_f32_16x16x32_f16((a),(b),(c),0,0,0)

static constexpr int LMAX   = 1032;
static constexpr int TSTEPS = 1032;

// ---------------- ws layout (bytes) ----------------
static constexpr size_t ZBYTES   = (size_t)256*32*LMAX*2;        // 16,908,288
static constexpr size_t OFF_ZA   = 0;                            // conv ping; later reused as y4x
static constexpr size_t OFF_ZB   = OFF_ZA + ZBYTES;
static constexpr size_t OFF_Y4   = OFF_ZA;                       // alias: y4x[(b*1032+t)*32+ch]
static constexpr size_t OFF_WH1F = OFF_ZB + ZBYTES;              // [128nt][16q][64lane][8] f16 = 2MB
static constexpr size_t OFF_WI2F = OFF_WH1F + (size_t)128*16*64*8*2;
static constexpr size_t OFF_WH2F = OFF_WI2F + (size_t)128*16*64*8*2;
static constexpr size_t OFF_WX1F = OFF_WH2F + (size_t)128*16*64*8*2;  // [128nt][64lane][8] f16 = 128KB
static constexpr size_t OFF_B1   = OFF_WX1F + (size_t)128*64*8*2;     // 2048 f32
static constexpr size_t OFF_B2   = OFF_B1 + (size_t)2048*4;
static constexpr size_t OFF_STATS= OFF_B2 + (size_t)2048*4;           // 4 x 64 f32
static constexpr size_t OFF_AB   = OFF_STATS + (size_t)4*64*4;
static constexpr size_t OFF_H1X  = OFF_AB + (size_t)4*64*4;           // [8g][4slot][32][512] f16 = 1MB
static constexpr size_t OFF_H2X  = OFF_H1X + (size_t)8*4*32*512*2;    // [8g][2slot][32][512] f16 = 0.5MB
static constexpr size_t OFF_FLAGS= OFF_H2X + (size_t)8*2*32*512*2;    // 8g x 32 flags x 16 u32 pad
// total ~41.9 MB

__device__ __forceinline__ float sigm(float x){ return 1.f/(1.f+__expf(-x)); }
__device__ __forceinline__ float tanh_f(float x){ float e=__expf(2.f*x); return (e-1.f)/(e+1.f); }

__device__ __forceinline__ u64 lda64(const void* p){
  return __hip_atomic_load((const u64*)p, __ATOMIC_RELAXED, __HIP_MEMORY_SCOPE_AGENT);
}
__device__ __forceinline__ void sta64(void* p, u64 v){
  __hip_atomic_store((u64*)p, v, __ATOMIC_RELAXED, __HIP_MEMORY_SCOPE_AGENT);
}
__device__ __forceinline__ uint32_t ldf(const uint32_t* p){
  return __hip_atomic_load(p, __ATOMIC_RELAXED, __HIP_MEMORY_SCOPE_AGENT);
}
__device__ __forceinline__ void stf(uint32_t* p, uint32_t v){
  __hip_atomic_store(p, v, __ATOMIC_RELAXED, __HIP_MEMORY_SCOPE_AGENT);
}

// stage 32x512 f16 (row-major, from agent-coherent global) into XOR-swizzled LDS buffer
__device__ __forceinline__ void stage32x512(uint8_t* dstbase, const f16* src, int tid){
  #pragma unroll
  for (int i=0;i<16;++i){
    int qq = tid + 256*i;              // u64-quad index over 32x512 f16
    int row = qq >> 7, cq = qq & 127;  // 128 quads/row
    u64 v = lda64((const u64*)src + qq);
    int cc = (cq>>1) ^ (row & 7);      // 16B-chunk swizzle
    *(u64*)(dstbase + (((row<<6) + cc)<<4) + ((cq&1)<<3)) = v;
  }
}
// read A-frag (16B) for row, k-block q, lane-quad lq from swizzled buffer
__device__ __forceinline__ half8 fragLDS(const uint8_t* base, int row, int q, int lq){
  return *(const half8*)(base + ((((row<<6)) + (((q<<2)+lq) ^ (row & 7)))<<4));
}

// ---------------- zero flags/stats ----------------
__global__ void k_zero(float* stats, uint32_t* flags){
  int bx = blockIdx.x, tid = threadIdx.x;
  if (bx == 16){ if (tid < 256) stats[tid] = 0.f; }
  else flags[bx*256 + tid] = 0u;
}

// ---------------- weight prep: W = U(512x128) @ V(128x2048) -> frag layout ----------------
// frag: value W[k][n] at dst[((nt*16+q)*64 + lane)*8 + j], nt=n>>4, q=k>>5, lane=((k>>3)&3)*16+(n&15), j=k&7
__global__ __launch_bounds__(256) void k_prep_W(f16* __restrict__ dst, const float* __restrict__ U, const float* __restrict__ V){
  __shared__ float sU[64][65];
  __shared__ float sV[64][68];
  const int tid = threadIdx.x;
  const int n0 = blockIdx.x*64, k0 = blockIdx.y*64;
  const int tx = tid & 15, ty = tid >> 4;
  float acc[4][4];
  #pragma unroll
  for (int a=0;a<4;++a){ acc[a][0]=0.f; acc[a][1]=0.f; acc[a][2]=0.f; acc[a][3]=0.f; }
  for (int rc=0; rc<2; ++rc){
    __syncthreads();
    #pragma unroll
    for (int i=0;i<16;++i){
      int f = tid + 256*i;
      int row = f>>6, col = f&63;
      sU[row][col] = U[(size_t)(k0+row)*128 + rc*64 + col];
      sV[row][col] = V[(size_t)(rc*64+row)*2048 + n0 + col];
    }
    __syncthreads();
    for (int rr=0; rr<64; ++rr){
      float4 bv = *(const float4*)&sV[rr][tx*4];
      #pragma unroll
      for (int a=0;a<4;++a){
        float av = sU[ty*4+a][rr];
        acc[a][0] += av*bv.x; acc[a][1] += av*bv.y; acc[a][2] += av*bv.z; acc[a][3] += av*bv.w;
      }
    }
  }
  #pragma unroll
  for (int a=0;a<4;++a){
    int k = k0 + ty*4 + a;
    int q = k>>5, lq2 = (k>>3)&3, j = k&7;
    #pragma unroll
    for (int c=0;c<4;++c){
      int n = n0 + tx*4 + c;
      int nt = n>>4, lmn = n&15;
      dst[(((size_t)nt*16 + q)*64 + (lq2*16+lmn))*8 + j] = (f16)acc[a][c];
    }
  }
}

// Wx1 = Ui1(32x128) @ Vi1(128x2048) -> frag [nt][64][8] (K=32, single q)
__global__ __launch_bounds__(256) void k_prep_Wx(f16* __restrict__ dst, const float* __restrict__ U, const float* __restrict__ V){
  __shared__ float sU[32][129];
  __shared__ float sV[128][68];
  const int tid = threadIdx.x, n0 = blockIdx.x*64;
  for (int f=tid; f<32*128; f+=256) sU[f>>7][f&127] = U[f];
  for (int f=tid; f<128*64; f+=256) sV[f>>6][f&63] = V[(size_t)(f>>6)*2048 + n0 + (f&63)];
  __syncthreads();
  int nn = tid & 63, kb = (tid>>6)*8;
  int n = n0 + nn;
  float acc[8];
  #pragma unroll
  for (int i=0;i<8;++i) acc[i]=0.f;
  for (int r=0;r<128;++r){
    float v = sV[r][nn];
    #pragma unroll
    for (int i=0;i<8;++i) acc[i] += sU[kb+i][r]*v;
  }
  int nt = n>>4, lmn = n&15;
  #pragma unroll
  for (int i=0;i<8;++i){
    int k = kb+i;
    dst[((size_t)nt*64 + (((k>>3)&3)*16 + lmn))*8 + (k&7)] = (f16)acc[i];
  }
}

__global__ void k_prep_bias(float* dst, const float* a, const float* b){
  int idx = blockIdx.x*256 + threadIdx.x;
  if (idx < 2048) dst[idx] = a[idx] + b[idx];
}

// ---------------- conv block (verified in R1/R2) ----------------
__global__ __launch_bounds__(256) void k_conv(
    const float* __restrict__ x0, const f16* __restrict__ zin,
    const float* __restrict__ abp,
    const float* __restrict__ dwk, const float* __restrict__ dwb,
    const float* __restrict__ pwk, const float* __restrict__ pwb,
    f16* __restrict__ zout, float* __restrict__ stats,
    int Lin, int Cin)
{
  const int tid = threadIdx.x;
  const int b = blockIdx.y;
  const int l = blockIdx.x*256 + tid;
  const int Lout = Lin + 2;
  __shared__ float sPw[32*32], sDw[32*7], sDb[32], sPb[32], sAb[64];
  __shared__ float sRed[2][4][32];
  for (int i=tid; i<Cin*32; i+=256) sPw[i] = pwk[i];
  for (int i=tid; i<Cin*7;  i+=256) sDw[i] = dwk[i];
  if (tid < Cin) sDb[tid] = dwb[tid];
  if (tid >= 64 && tid < 96) sPb[tid-64] = pwb[tid-64];
  if (abp != nullptr && tid >= 128 && tid < 192) sAb[tid-128] = abp[tid-128];
  __syncthreads();

  float acc[32];
  #pragma unroll
  for (int o=0;o<32;++o) acc[o] = sPb[o];
  const bool act = (l < Lout);
  if (act){
    for (int c=0;c<Cin;++c){
      float s = sDb[c];
      #pragma unroll
      for (int k=0;k<7;++k){
        int li = l + k - 4;
        float v = 0.f;
        if (li >= 0 && li < Lin){
          if (x0) v = x0[((size_t)b*1024 + li)*16 + c];
          else {
            float z = (float)zin[((size_t)b*32 + c)*LMAX + li];
            v = fmaxf(sAb[c]*z + sAb[32+c], 0.f);
          }
        }
        s += sDw[c*7+k]*v;
      }
      #pragma unroll
      for (int o=0;o<32;++o) acc[o] += sPw[o*Cin + c]*s;
    }
    #pragma unroll
    for (int o=0;o<32;++o) zout[((size_t)b*32 + o)*LMAX + l] = (f16)acc[o];
  }
  const int lane = tid & 63, wv = tid >> 6;
  for (int o=0;o<32;++o){
    float v = act ? acc[o] : 0.f;
    float q = v*v;
    #pragma unroll
    for (int m=1;m<64;m<<=1){ v += __shfl_xor(v,m); q += __shfl_xor(q,m); }
    if (lane == 0){ sRed[0][wv][o] = v; sRed[1][wv][o] = q; }
  }
  __syncthreads();
  if (tid < 32){
    float v = sRed[0][0][tid]+sRed[0][1][tid]+sRed[0][2][tid]+sRed[0][3][tid];
    float q = sRed[1][0][tid]+sRed[1][1][tid]+sRed[1][2][tid]+sRed[1][3][tid];
    atomicAdd(&stats[tid], v);
    atomicAdd(&stats[32+tid], q);
  }
}

__global__ void k_bnfin(const float* __restrict__ stats, const float* __restrict__ g,
                        const float* __restrict__ beta, float* __restrict__ ab, float inv_n)
{
  int o = threadIdx.x;
  if (o < 32){
    float m = stats[o]*inv_n;
    float var = stats[32+o]*inv_n - m*m;
    float a = g[o]*rsqrtf(var + 1e-5f);
    ab[o] = a; ab[32+o] = beta[o] - m*a;
  }
}

// ---------------- y4 precompute: y4x[(b*1032+t)*32+ch] = relu(bn(zB)) ----------------
__global__ __launch_bounds__(256) void k_y4(const f16* __restrict__ z, const float* __restrict__ ab, f16* __restrict__ y){
  __shared__ f16 sT[32][264];
  __shared__ float sA[64];
  const int b = blockIdx.x, t0 = blockIdx.y*256, tid = threadIdx.x;
  if (tid < 64) sA[tid] = ab[tid];
  __syncthreads();
  #pragma unroll
  for (int i=0;i<8;++i){
    int f = tid + 256*i;
    int ch = f >> 6, tq = f & 63;
    int t = t0 + tq*4;
    if (t < 1032){
      u64 v = *(const u64*)(z + ((size_t)(b*32+ch)*1032 + t));
      union { u64 u; f16 h[4]; } cv; cv.u = v;
      float a = sA[ch], bb = sA[32+ch];
      #pragma unroll
      for (int j=0;j<4;++j) cv.h[j] = (f16)fmaxf(a*(float)cv.h[j] + bb, 0.f);
      *(u64*)&sT[ch][tq*4] = cv.u;
    }
  }
  __syncthreads();
  int t = t0 + tid;
  if (t < 1032){
    union { uint4 v; f16 h[8]; } o[4];
    #pragma unroll
    for (int k=0;k<4;++k)
      #pragma unroll
      for (int j=0;j<8;++j) o[k].h[j] = sT[k*8+j][t - t0];
    uint4* dst = (uint4*)(y + ((size_t)b*1032 + t)*32);
    #pragma unroll
    for (int k=0;k<4;++k) dst[k] = o[k].v;
  }
}

// ---------------- persistent 2-layer LSTM: 8 groups x 2 roles x 16 col-split blocks ----------------
__global__ __launch_bounds__(256,1) void k_lstm(
  const f16* __restrict__ y4x,
  const f16* __restrict__ Wx1F, const f16* __restrict__ Wh1F,
  const f16* __restrict__ Wi2F, const f16* __restrict__ Wh2F,
  const float* __restrict__ bias1, const float* __restrict__ bias2,
  f16* __restrict__ h1x, f16* __restrict__ h2x,
  uint32_t* __restrict__ flags,
  const float* __restrict__ fcw, const float* __restrict__ fcb,
  float* __restrict__ outp)
{
  const int tid  = threadIdx.x;
  const int lane = tid & 63;
  const int w    = tid >> 6;      // wave = gate index s
  const int lm   = lane & 15;
  const int lq   = lane >> 4;
  const int lq8  = lq*8;
  const int g    = blockIdx.x & 7;              // group (XCD hint)
  const int idx  = blockIdx.x >> 3;             // 0..31
  const int role = idx >> 4;                    // 0 = layer1, 1 = layer2
  const int b    = idx & 15;                    // unit-slice: units b*32..b*32+31

  __shared__ __align__(16) uint8_t smem[65536]; // buf0 [0,32K) + buf1 [32K,64K); sGate(16KB f32) aliases buf0
  uint8_t* buf0 = smem;
  uint8_t* buf1 = smem + 32768;
  float* sGate = (float*)smem;                  // [4 gates][32 rows][32 units]

  uint32_t* FH1 = flags + (size_t)g*512;        // 16 flags, stride 16 u32 (64B)
  uint32_t* FH2 = flags + (size_t)g*512 + 256;

  const float* biasL = role ? bias2 : bias1;
  float bs[2];
  #pragma unroll
  for (int ct=0; ct<2; ++ct) bs[ct] = biasL[w*512 + b*32 + ct*16 + lm];

  const int nt0 = w*32 + b*2;
  f16* hdst_base = role ? h2x + (size_t)g*2*32*512 : h1x + (size_t)g*4*32*512;

  float creg[4] = {0.f,0.f,0.f,0.f};
  const int cr_row = tid >> 3, cr_u0 = (tid & 7)*4;

  if (role == 0){
    // ---------------- layer-1 producer ----------------
    half8 wx[2];
    half8 wB[2][16];
    #pragma unroll
    for (int ct=0; ct<2; ++ct){
      wx[ct] = *(const half8*)&Wx1F[((size_t)(nt0+ct)*64 + lane)*8];
      #pragma unroll
      for (int q=0;q<16;++q)
        wB[ct][q] = *(const half8*)&Wh1F[(((size_t)(nt0+ct)*16 + q)*64 + lane)*8];
    }
    #pragma unroll 1
    for (int t=0; t<TSTEPS; ++t){
      // prefetch y4 A-frags (independent of flags)
      half8 ya0 = *(const half8*)(y4x + ((size_t)(g*32 + lm)*1032 + t)*32 + lq8);
      half8 ya1 = *(const half8*)(y4x + ((size_t)(g*32 + 16 + lm)*1032 + t)*32 + lq8);
      // waits: peers' h1(t-1); consumers past h1(t-4) before we overwrite slot t&3
      if (tid < 16 && t >= 1){
        while ((int)ldf(&FH1[tid*16]) < t) __builtin_amdgcn_s_sleep(1);
      }
      if (tid >= 16 && tid < 32 && t >= 4){
        while ((int)ldf(&FH2[(tid-16)*16]) < t-3) __builtin_amdgcn_s_sleep(1);
      }
      __syncthreads();
      if (t >= 1){
        stage32x512(buf0, h1x + ((size_t)(g*4 + ((t-1)&3))*32*512), tid);
      }
      __syncthreads();
      floatx4 acc[2][2];
      #pragma unroll
      for (int ct=0; ct<2; ++ct){
        acc[ct][0] = (floatx4){bs[ct],bs[ct],bs[ct],bs[ct]};
        acc[ct][1] = acc[ct][0];
      }
      acc[0][0] = MFMA(ya0, wx[0], acc[0][0]);
      acc[0][1] = MFMA(ya1, wx[0], acc[0][1]);
      acc[1][0] = MFMA(ya0, wx[1], acc[1][0]);
      acc[1][1] = MFMA(ya1, wx[1], acc[1][1]);
      if (t >= 1){
        #pragma unroll
        for (int q=0;q<16;++q){
          half8 a0 = fragLDS(buf0, lm,    q, lq);
          half8 a1 = fragLDS(buf0, 16+lm, q, lq);
          acc[0][0] = MFMA(a0, wB[0][q], acc[0][0]);
          acc[0][1] = MFMA(a1, wB[0][q], acc[0][1]);
          acc[1][0] = MFMA(a0, wB[1][q], acc[1][0]);
          acc[1][1] = MFMA(a1, wB[1][q], acc[1][1]);
        }
      }
      __syncthreads();   // done reading buf0; sGate aliases it
      #pragma unroll
      for (int ct=0; ct<2; ++ct)
        #pragma unroll
        for (int rt=0; rt<2; ++rt)
          #pragma unroll
          for (int r=0;r<4;++r)
            sGate[w*1024 + (rt*16 + lq*4 + r)*32 + ct*16 + lm] = acc[ct][rt][r];
      __syncthreads();
      {
        union { u64 uu; f16 h[4]; } hv;
        #pragma unroll
        for (int j=0;j<4;++j){
          int u = cr_u0 + j;
          float iv = sGate[0*1024 + cr_row*32 + u];
          float fv = sGate[1*1024 + cr_row*32 + u];
          float gv = sGate[2*1024 + cr_row*32 + u];
          float ov = sGate[3*1024 + cr_row*32 + u];
          float c = sigm(fv)*creg[j] + sigm(iv)*tanh_f(gv);
          creg[j] = c;
          hv.h[j] = (f16)(sigm(ov)*tanh_f(c));
        }
        f16* dst = hdst_base + (size_t)(t&3)*32*512 + cr_row*512 + b*32 + cr_u0;
        sta64(dst, hv.uu);
      }
      asm volatile("s_waitcnt vmcnt(0)" ::: "memory");
      __syncthreads();
      if (tid == 0) stf(&FH1[b*16], (uint32_t)(t+1));
    }
  } else {
    // ---------------- layer-2 consumer ----------------
    half8 wA[2][16];
    half8 wB[2][16];
    #pragma unroll
    for (int ct=0; ct<2; ++ct)
      #pragma unroll
      for (int q=0;q<16;++q){
        wA[ct][q] = *(const half8*)&Wi2F[(((size_t)(nt0+ct)*16 + q)*64 + lane)*8];
        wB[ct][q] = *(const half8*)&Wh2F[(((size_t)(nt0+ct)*16 + q)*64 + lane)*8];
      }
    #pragma unroll 1
    for (int t=0; t<TSTEPS; ++t){
      if (tid < 16){
        while ((int)ldf(&FH1[tid*16]) < t+1) __builtin_amdgcn_s_sleep(1);
      }
      if (tid >= 16 && tid < 32 && t >= 1){
        while ((int)ldf(&FH2[(tid-16)*16]) < t) __builtin_amdgcn_s_sleep(1);
      }
      __syncthreads();
      stage32x512(buf0, h1x + ((size_t)(g*4 + (t&3))*32*512), tid);
      if (t >= 1)
        stage32x512(buf1, h2x + ((size_t)(g*2 + ((t-1)&1))*32*512), tid);
      __syncthreads();
      floatx4 acc[2][2];
      #pragma unroll
      for (int ct=0; ct<2; ++ct){
        acc[ct][0] = (floatx4){bs[ct],bs[ct],bs[ct],bs[ct]};
        acc[ct][1] = acc[ct][0];
      }
      #pragma unroll
      for (int q=0;q<16;++q){
        half8 a0 = fragLDS(buf0, lm,    q, lq);
        half8 a1 = fragLDS(buf0, 16+lm, q, lq);
        acc[0][0] = MFMA(a0, wA[0][q], acc[0][0]);
        acc[0][1] = MFMA(a1, wA[0][q], acc[0][1]);
        acc[1][0] = MFMA(a0, wA[1][q], acc[1][0]);
        acc[1][1] = MFMA(a1, wA[1][q], acc[1][1]);
      }
      if (t >= 1){
        #pragma unroll
        for (int q=0;q<16;++q){
          half8 a0 = fragLDS(buf1, lm,    q, lq);
          half8 a1 = fragLDS(buf1, 16+lm, q, lq);
          acc[0][0] = MFMA(a0, wB[0][q], acc[0][0]);
          acc[0][1] = MFMA(a1, wB[0][q], acc[0][1]);
          acc[1][0] = MFMA(a0, wB[1][q], acc[1][0]);
          acc[1][1] = MFMA(a1, wB[1][q], acc[1][1]);
        }
      }
      __syncthreads();
      #pragma unroll
      for (int ct=0; ct<2; ++ct)
        #pragma unroll
        for (int rt=0; rt<2; ++rt)
          #pragma unroll
          for (int r=0;r<4;++r)
            sGate[w*1024 + (rt*16 + lq*4 + r)*32 + ct*16 + lm] = acc[ct][rt][r];
      __syncthreads();
      {
        union { u64 uu; f16 h[4]; } hv;
        #pragma unroll
        for (int j=0;j<4;++j){
          int u = cr_u0 + j;
          float iv = sGate[0*1024 + cr_row*32 + u];
          float fv = sGate[1*1024 + cr_row*32 + u];
          float gv = sGate[2*1024 + cr_row*32 + u];
          float ov = sGate[3*1024 + cr_row*32 + u];
          float c = sigm(fv)*creg[j] + sigm(iv)*tanh_f(gv);
          creg[j] = c;
          hv.h[j] = (f16)(sigm(ov)*tanh_f(c));
        }
        f16* dst = hdst_base + (size_t)(t&1)*32*512 + cr_row*512 + b*32 + cr_u0;
        sta64(dst, hv.uu);
      }
      asm volatile("s_waitcnt vmcnt(0)" ::: "memory");
      __syncthreads();
      if (tid == 0) stf(&FH2[b*16], (uint32_t)(t+1));
    }
    // ---------- epilogue: out = h2(T-1) @ fc_w^T + fc_b ----------
    if (b == 0){
      if (tid < 16){
        while ((int)ldf(&FH2[tid*16]) < TSTEPS) __builtin_amdgcn_s_sleep(1);
      }
      __syncthreads();
      const f16* hbase = h2x + ((size_t)(g*2 + ((TSTEPS-1)&1))*32*512);
      for (int e = tid; e < 320; e += 256){
        int row = e/10, nc = e%10;
        float s = fcb[nc];
        const float* wv = fcw + (size_t)nc*512;
        const u64* hp = (const u64*)(hbase + row*512);
        for (int k4=0;k4<128;++k4){
          union { u64 uu; f16 h[4]; } cv; cv.uu = lda64(hp + k4);
          #pragma unroll
          for (int i2=0;i2<4;++i2) s += (float)cv.h[i2]*wv[k4*4+i2];
        }
        outp[(size_t)(g*32+row)*10 + nc] = s;
      }
    }
  }
}

// ---------------- host ----------------
extern "C" void kernel_launch(void* const* d_in, const int* in_sizes, int n_in,
                              void* d_out, int out_size, void* d_ws, size_t ws_size,
                              hipStream_t stream)
{
  (void)in_sizes; (void)n_in; (void)out_size; (void)ws_size;
  const float* x = (const float*)d_in[0];
  auto F = [&](int i){ return (const float*)d_in[i]; };
  const float *Ui1=F(25), *Vi1=F(26), *Uh1=F(27), *Vh1=F(28), *bi1=F(29), *bh1=F(30);
  const float *Ui2=F(31), *Vi2=F(32), *Uh2=F(33), *Vh2=F(34), *bi2=F(35), *bh2=F(36);
  const float *fcw=F(37), *fcb=F(38);

  uint8_t* ws = (uint8_t*)d_ws;
  f16* zA   = (f16*)(ws + OFF_ZA);
  f16* zB   = (f16*)(ws + OFF_ZB);
  f16* y4x  = (f16*)(ws + OFF_Y4);
  f16* Wh1F = (f16*)(ws + OFF_WH1F);
  f16* Wi2F = (f16*)(ws + OFF_WI2F);
  f16* Wh2F = (f16*)(ws + OFF_WH2F);
  f16* Wx1F = (f16*)(ws + OFF_WX1F);
  float* bias1 = (float*)(ws + OFF_B1);
  float* bias2 = (float*)(ws + OFF_B2);
  float* stats = (float*)(ws + OFF_STATS);
  float* ab    = (float*)(ws + OFF_AB);
  f16* h1x  = (f16*)(ws + OFF_H1X);
  f16* h2x  = (f16*)(ws + OFF_H2X);
  uint32_t* flags = (uint32_t*)(ws + OFF_FLAGS);
  float* outp = (float*)d_out;

  k_zero<<<17, 256, 0, stream>>>(stats, flags);

  k_prep_W<<<dim3(32,8), 256, 0, stream>>>(Wh1F, Uh1, Vh1);
  k_prep_W<<<dim3(32,8), 256, 0, stream>>>(Wi2F, Ui2, Vi2);
  k_prep_W<<<dim3(32,8), 256, 0, stream>>>(Wh2F, Uh2, Vh2);
  k_prep_Wx<<<32, 256, 0, stream>>>(Wx1F, Ui1, Vi1);
  k_prep_bias<<<8, 256, 0, stream>>>(bias1, bi1, bh1);
  k_prep_bias<<<8, 256, 0, stream>>>(bias2, bi2, bh2);

  dim3 cgrid(5, 256);
  k_conv<<<cgrid, 256, 0, stream>>>(x, nullptr, nullptr, F(1), F(2), F(3), F(4),
                                    zA, stats + 0*64, 1024, 16);
  k_bnfin<<<1, 64, 0, stream>>>(stats + 0*64, F(5), F(6), ab + 0*64, 1.f/(256.f*1026.f));
  k_conv<<<cgrid, 256, 0, stream>>>(nullptr, zA, ab + 0*64, F(7), F(8), F(9), F(10),
                                    zB, stats + 1*64, 1026, 32);
  k_bnfin<<<1, 64, 0, stream>>>(stats + 1*64, F(11), F(12), ab + 1*64, 1.f/(256.f*1028.f));
  k_conv<<<cgrid, 256, 0, stream>>>(nullptr, zB, ab + 1*64, F(13), F(14), F(15), F(16),
                                    zA, stats + 2*64, 1028, 32);
  k_bnfin<<<1, 64, 0, stream>>>(stats + 2*64, F(17), F(18), ab + 2*64, 1.f/(256.f*1030.f));
  k_conv<<<cgrid, 256, 0, stream>>>(nullptr, zA, ab + 2*64, F(19), F(20), F(21), F(22),
                                    zB, stats + 3*64, 1030, 32);
  k_bnfin<<<1, 64, 0, stream>>>(stats + 3*64, F(23), F(24), ab + 3*64, 1.f/(256.f*1032.f));

  // y4 precompute (overwrites zA region — conv chain done with it)
  k_y4<<<dim3(256,5), 256, 0, stream>>>(zB, ab + 3*64, y4x);

  k_lstm<<<256, 256, 0, stream>>>(y4x,
                                  Wx1F, Wh1F, Wi2F, Wh2F,
                                  bias1, bias2,
                                  h1x, h2x, flags,
                                  fcw, fcb, outp);
}

// Round 4
// 6312.938 us; speedup vs baseline: 1.4989x; 1.4989x over previous
//
#include <hip/hip_runtime.h>
#include <stdint.h>
#include <stddef.h>
#include <limits.h>

typedef _Float16 f16;
typedef _Float16 half8 __attribute__((ext_vector_type(8)));
typedef float floatx4 __attribute__((ext_vector_type(4)));
typedef unsigned long long u64;

#define MFMA(a,b,c) __builtin_amdgcn_mfma_f32_16x16x32_f16((a),(b),(c),0,0,0)

static constexpr int LMAX   = 1032;
static constexpr int TSTEPS = 1032;

// ---------------- ws layout (bytes) ----------------
static constexpr size_t ZBYTES   = (size_t)256*32*LMAX*2;        // 16,908,288
static constexpr size_t OFF_ZA   = 0;                            // conv ping; later reused as y4x
static constexpr size_t OFF_ZB   = OFF_ZA + ZBYTES;
static constexpr size_t OFF_Y4   = OFF_ZA;                       // alias
static constexpr size_t OFF_WH1F = OFF_ZB + ZBYTES;              // [128nt][16q][64lane][8] f16 = 2MB
static constexpr size_t OFF_WI2F = OFF_WH1F + (size_t)128*16*64*8*2;
static constexpr size_t OFF_WH2F = OFF_WI2F + (size_t)128*16*64*8*2;
static constexpr size_t OFF_WX1F = OFF_WH2F + (size_t)128*16*64*8*2;  // 128KB
static constexpr size_t OFF_B1   = OFF_WX1F + (size_t)128*64*8*2;
static constexpr size_t OFF_B2   = OFF_B1 + (size_t)2048*4;
static constexpr size_t OFF_STATS= OFF_B2 + (size_t)2048*4;
static constexpr size_t OFF_AB   = OFF_STATS + (size_t)4*64*4;
static constexpr size_t OFF_H1X  = OFF_AB + (size_t)4*64*4;           // [8g][8slot][32][512] f16 = 2MB
static constexpr size_t OFF_H2X  = OFF_H1X + (size_t)8*8*32*512*2;    // [8g][4slot][32][512] f16 = 1MB
static constexpr size_t OFF_FLAGS= OFF_H2X + (size_t)8*4*32*512*2;    // 8g x 32 u32 (128B/group)
// total ~43.3 MB

__device__ __forceinline__ float sigm(float x){ return 1.f/(1.f+__expf(-x)); }
__device__ __forceinline__ float tanh_f(float x){ float e=__expf(2.f*x); return (e-1.f)/(e+1.f); }

__device__ __forceinline__ void sta64(void* p, u64 v){
  __hip_atomic_store((u64*)p, v, __ATOMIC_RELAXED, __HIP_MEMORY_SCOPE_AGENT);
}
__device__ __forceinline__ u64 lda64(const void* p){
  return __hip_atomic_load((const u64*)p, __ATOMIC_RELAXED, __HIP_MEMORY_SCOPE_AGENT);
}
__device__ __forceinline__ uint32_t ldf(const uint32_t* p){
  return __hip_atomic_load(p, __ATOMIC_RELAXED, __HIP_MEMORY_SCOPE_AGENT);
}
__device__ __forceinline__ void stf(uint32_t* p, uint32_t v){
  __hip_atomic_store(p, v, __ATOMIC_RELAXED, __HIP_MEMORY_SCOPE_AGENT);
}
// 16B coherent (L1/L2-stale-safe) load, manually waited via vmcnt0()
__device__ __forceinline__ float4 ldg16(const void* p){
  float4 r;
  asm volatile("global_load_dwordx4 %0, %1, off sc0 sc1" : "=v"(r) : "v"(p) : "memory");
  return r;
}
__device__ __forceinline__ void vmcnt0(){
  asm volatile("s_waitcnt vmcnt(0)" ::: "memory");
}

// poll one 128B flag region with full wave0: lanes<16 check [lane] >= t1, lanes 16..31 check [lane] >= t2
__device__ __forceinline__ void pollWave(const uint32_t* fl, int t1, int t2){
  const int lane = threadIdx.x & 63;
  int tgt = (lane < 16) ? t1 : ((lane < 32) ? t2 : INT_MIN);
  if (tgt <= 0) tgt = INT_MIN;
  while (true){
    uint32_t v = ldf(&fl[lane & 31]);
    if (__all((int)v >= tgt)) break;
    __builtin_amdgcn_s_sleep(1);
  }
}

// stage 32x512 f16: issue 8x16B coherent loads / thread
__device__ __forceinline__ void stageIssue(float4* r, const f16* src, int tid){
  #pragma unroll
  for (int i=0;i<8;++i){
    int qq = tid + 256*i;
    r[i] = ldg16(src + (size_t)qq*8);
  }
}
// write staged regs into swizzled LDS: chunk' = chunk ^ (row&15); wave writes one contiguous permuted row
__device__ __forceinline__ void stageWrite(uint8_t* base, const float4* r, int tid){
  #pragma unroll
  for (int i=0;i<8;++i){
    int qq = tid + 256*i;
    int row = qq >> 6, ck = qq & 63;
    int cs = ck ^ (row & 15);
    *(float4*)(base + ((row<<6) + cs)*16) = r[i];
  }
}
// A-frag read: 16B at (row, k-chunk q*4+lq), swizzled
__device__ __forceinline__ half8 fragLDS(const uint8_t* base, int row, int q, int lq){
  return *(const half8*)(base + (((row<<6)) + (((q<<2)+lq) ^ (row & 15)))*16);
}

// ---------------- zero flags/stats ----------------
__global__ void k_zero(float* stats, uint32_t* flags){
  int bx = blockIdx.x, tid = threadIdx.x;
  if (bx == 4){ if (tid < 256) stats[tid] = 0.f; }
  else flags[bx*256 + tid] = 0u;
}

// ---------------- weight prep: W = U(512x128) @ V(128x2048) -> frag layout ----------------
__global__ __launch_bounds__(256) void k_prep_W(f16* __restrict__ dst, const float* __restrict__ U, const float* __restrict__ V){
  __shared__ float sU[64][65];
  __shared__ float sV[64][68];
  const int tid = threadIdx.x;
  const int n0 = blockIdx.x*64, k0 = blockIdx.y*64;
  const int tx = tid & 15, ty = tid >> 4;
  float acc[4][4];
  #pragma unroll
  for (int a=0;a<4;++a){ acc[a][0]=0.f; acc[a][1]=0.f; acc[a][2]=0.f; acc[a][3]=0.f; }
  for (int rc=0; rc<2; ++rc){
    __syncthreads();
    #pragma unroll
    for (int i=0;i<16;++i){
      int f = tid + 256*i;
      int row = f>>6, col = f&63;
      sU[row][col] = U[(size_t)(k0+row)*128 + rc*64 + col];
      sV[row][col] = V[(size_t)(rc*64+row)*2048 + n0 + col];
    }
    __syncthreads();
    for (int rr=0; rr<64; ++rr){
      float4 bv = *(const float4*)&sV[rr][tx*4];
      #pragma unroll
      for (int a=0;a<4;++a){
        float av = sU[ty*4+a][rr];
        acc[a][0] += av*bv.x; acc[a][1] += av*bv.y; acc[a][2] += av*bv.z; acc[a][3] += av*bv.w;
      }
    }
  }
  #pragma unroll
  for (int a=0;a<4;++a){
    int k = k0 + ty*4 + a;
    int q = k>>5, lq2 = (k>>3)&3, j = k&7;
    #pragma unroll
    for (int c=0;c<4;++c){
      int n = n0 + tx*4 + c;
      int nt = n>>4, lmn = n&15;
      dst[(((size_t)nt*16 + q)*64 + (lq2*16+lmn))*8 + j] = (f16)acc[a][c];
    }
  }
}

__global__ __launch_bounds__(256) void k_prep_Wx(f16* __restrict__ dst, const float* __restrict__ U, const float* __restrict__ V){
  __shared__ float sU[32][129];
  __shared__ float sV[128][68];
  const int tid = threadIdx.x, n0 = blockIdx.x*64;
  for (int f=tid; f<32*128; f+=256) sU[f>>7][f&127] = U[f];
  for (int f=tid; f<128*64; f+=256) sV[f>>6][f&63] = V[(size_t)(f>>6)*2048 + n0 + (f&63)];
  __syncthreads();
  int nn = tid & 63, kb = (tid>>6)*8;
  int n = n0 + nn;
  float acc[8];
  #pragma unroll
  for (int i=0;i<8;++i) acc[i]=0.f;
  for (int r=0;r<128;++r){
    float v = sV[r][nn];
    #pragma unroll
    for (int i=0;i<8;++i) acc[i] += sU[kb+i][r]*v;
  }
  int nt = n>>4, lmn = n&15;
  #pragma unroll
  for (int i=0;i<8;++i){
    int k = kb+i;
    dst[((size_t)nt*64 + (((k>>3)&3)*16 + lmn))*8 + (k&7)] = (f16)acc[i];
  }
}

__global__ void k_prep_bias(float* dst, const float* a, const float* b){
  int idx = blockIdx.x*256 + threadIdx.x;
  if (idx < 2048) dst[idx] = a[idx] + b[idx];
}

// ---------------- conv block (verified R1-R3) ----------------
__global__ __launch_bounds__(256) void k_conv(
    const float* __restrict__ x0, const f16* __restrict__ zin,
    const float* __restrict__ abp,
    const float* __restrict__ dwk, const float* __restrict__ dwb,
    const float* __restrict__ pwk, const float* __restrict__ pwb,
    f16* __restrict__ zout, float* __restrict__ stats,
    int Lin, int Cin)
{
  const int tid = threadIdx.x;
  const int b = blockIdx.y;
  const int l = blockIdx.x*256 + tid;
  const int Lout = Lin + 2;
  __shared__ float sPw[32*32], sDw[32*7], sDb[32], sPb[32], sAb[64];
  __shared__ float sRed[2][4][32];
  for (int i=tid; i<Cin*32; i+=256) sPw[i] = pwk[i];
  for (int i=tid; i<Cin*7;  i+=256) sDw[i] = dwk[i];
  if (tid < Cin) sDb[tid] = dwb[tid];
  if (tid >= 64 && tid < 96) sPb[tid-64] = pwb[tid-64];
  if (abp != nullptr && tid >= 128 && tid < 192) sAb[tid-128] = abp[tid-128];
  __syncthreads();

  float acc[32];
  #pragma unroll
  for (int o=0;o<32;++o) acc[o] = sPb[o];
  const bool act = (l < Lout);
  if (act){
    for (int c=0;c<Cin;++c){
      float s = sDb[c];
      #pragma unroll
      for (int k=0;k<7;++k){
        int li = l + k - 4;
        float v = 0.f;
        if (li >= 0 && li < Lin){
          if (x0) v = x0[((size_t)b*1024 + li)*16 + c];
          else {
            float z = (float)zin[((size_t)b*32 + c)*LMAX + li];
            v = fmaxf(sAb[c]*z + sAb[32+c], 0.f);
          }
        }
        s += sDw[c*7+k]*v;
      }
      #pragma unroll
      for (int o=0;o<32;++o) acc[o] += sPw[o*Cin + c]*s;
    }
    #pragma unroll
    for (int o=0;o<32;++o) zout[((size_t)b*32 + o)*LMAX + l] = (f16)acc[o];
  }
  const int lane = tid & 63, wv = tid >> 6;
  for (int o=0;o<32;++o){
    float v = act ? acc[o] : 0.f;
    float q = v*v;
    #pragma unroll
    for (int m=1;m<64;m<<=1){ v += __shfl_xor(v,m); q += __shfl_xor(q,m); }
    if (lane == 0){ sRed[0][wv][o] = v; sRed[1][wv][o] = q; }
  }
  __syncthreads();
  if (tid < 32){
    float v = sRed[0][0][tid]+sRed[0][1][tid]+sRed[0][2][tid]+sRed[0][3][tid];
    float q = sRed[1][0][tid]+sRed[1][1][tid]+sRed[1][2][tid]+sRed[1][3][tid];
    atomicAdd(&stats[tid], v);
    atomicAdd(&stats[32+tid], q);
  }
}

__global__ void k_bnfin(const float* __restrict__ stats, const float* __restrict__ g,
                        const float* __restrict__ beta, float* __restrict__ ab, float inv_n)
{
  int o = threadIdx.x;
  if (o < 32){
    float m = stats[o]*inv_n;
    float var = stats[32+o]*inv_n - m*m;
    float a = g[o]*rsqrtf(var + 1e-5f);
    ab[o] = a; ab[32+o] = beta[o] - m*a;
  }
}

// ---------------- y4 precompute ----------------
__global__ __launch_bounds__(256) void k_y4(const f16* __restrict__ z, const float* __restrict__ ab, f16* __restrict__ y){
  __shared__ f16 sT[32][264];
  __shared__ float sA[64];
  const int b = blockIdx.x, t0 = blockIdx.y*256, tid = threadIdx.x;
  if (tid < 64) sA[tid] = ab[tid];
  __syncthreads();
  #pragma unroll
  for (int i=0;i<8;++i){
    int f = tid + 256*i;
    int ch = f >> 6, tq = f & 63;
    int t = t0 + tq*4;
    if (t < 1032){
      u64 v = *(const u64*)(z + ((size_t)(b*32+ch)*1032 + t));
      union { u64 u; f16 h[4]; } cv; cv.u = v;
      float a = sA[ch], bb = sA[32+ch];
      #pragma unroll
      for (int j=0;j<4;++j) cv.h[j] = (f16)fmaxf(a*(float)cv.h[j] + bb, 0.f);
      *(u64*)&sT[ch][tq*4] = cv.u;
    }
  }
  __syncthreads();
  int t = t0 + tid;
  if (t < 1032){
    union { uint4 v; f16 h[8]; } o[4];
    #pragma unroll
    for (int k=0;k<4;++k)
      #pragma unroll
      for (int j=0;j<8;++j) o[k].h[j] = sT[k*8+j][t - t0];
    uint4* dst = (uint4*)(y + ((size_t)b*1032 + t)*32);
    #pragma unroll
    for (int k=0;k<4;++k) dst[k] = o[k].v;
  }
}

// ---------------- persistent 2-layer LSTM: 8 groups x (16 L1 + 16 L2 blocks) ----------------
__global__ __launch_bounds__(256,1) void k_lstm(
  const f16* __restrict__ y4x,
  const f16* __restrict__ Wx1F, const f16* __restrict__ Wh1F,
  const f16* __restrict__ Wi2F, const f16* __restrict__ Wh2F,
  const float* __restrict__ bias1, const float* __restrict__ bias2,
  f16* __restrict__ h1x, f16* __restrict__ h2x,
  uint32_t* __restrict__ flags,
  const float* __restrict__ fcw, const float* __restrict__ fcb,
  float* __restrict__ outp)
{
  const int tid  = threadIdx.x;
  const int lane = tid & 63;
  const int w    = tid >> 6;      // wave = gate index s
  const int lm   = lane & 15;
  const int lq   = lane >> 4;
  const int lq8  = lq*8;
  const int g    = blockIdx.x & 7;              // group (XCD hint)
  const int idx  = blockIdx.x >> 3;             // 0..31
  const int role = idx >> 4;                    // 0 = layer1, 1 = layer2
  const int b    = idx & 15;                    // unit-slice: units b*32..b*32+31

  // 82,432 B static LDS -> exactly 1 block/CU (2x82,432 > 163,840)
  __shared__ __align__(16) uint8_t bufA[32768];
  __shared__ __align__(16) uint8_t bufB[32768];
  __shared__ float sGate[4*32*33];              // padded stride 33

  uint32_t* fl = flags + (size_t)g*32;          // [0..15]=FH1(producers), [16..31]=FHC(consumers)

  const float* biasL = role ? bias2 : bias1;
  float bs[2];
  #pragma unroll
  for (int ct=0; ct<2; ++ct) bs[ct] = biasL[w*512 + b*32 + ct*16 + lm];

  const int nt0 = w*32 + b*2;
  f16* hdst_base = role ? h2x + (size_t)g*4*32*512 : h1x + (size_t)g*8*32*512;

  float creg[4] = {0.f,0.f,0.f,0.f};
  const int cr_row = tid >> 3, cr_u0 = (tid & 7)*4;

  if (role == 0){
    // ---------------- layer-1 producer ----------------
    half8 wx[2];
    half8 wB[2][16];
    #pragma unroll
    for (int ct=0; ct<2; ++ct){
      wx[ct] = *(const half8*)&Wx1F[((size_t)(nt0+ct)*64 + lane)*8];
      #pragma unroll
      for (int q=0;q<16;++q)
        wB[ct][q] = *(const half8*)&Wh1F[(((size_t)(nt0+ct)*16 + q)*64 + lane)*8];
    }
    #pragma unroll 1
    for (int t=0; t<TSTEPS; ++t){
      // y4 prefetch (independent of flags)
      half8 ya0 = *(const half8*)(y4x + ((size_t)(g*32 + lm)*1032 + t)*32 + lq8);
      half8 ya1 = *(const half8*)(y4x + ((size_t)(g*32 + 16 + lm)*1032 + t)*32 + lq8);
      if (w == 0) pollWave(fl, t, t-7);   // peers' h1(t-1); consumers done t-8
      __syncthreads();
      float4 st[8];
      if (t >= 1) stageIssue(st, h1x + ((size_t)(g*8 + ((t-1)&7))*32*512), tid);
      floatx4 acc[2][2];
      #pragma unroll
      for (int ct=0; ct<2; ++ct){
        acc[ct][0] = (floatx4){bs[ct],bs[ct],bs[ct],bs[ct]};
        acc[ct][1] = acc[ct][0];
      }
      acc[0][0] = MFMA(ya0, wx[0], acc[0][0]);
      acc[0][1] = MFMA(ya1, wx[0], acc[0][1]);
      acc[1][0] = MFMA(ya0, wx[1], acc[1][0]);
      acc[1][1] = MFMA(ya1, wx[1], acc[1][1]);
      if (t >= 1){
        vmcnt0();
        stageWrite(bufA, st, tid);
      }
      __syncthreads();
      if (t >= 1){
        #pragma unroll
        for (int q=0;q<16;++q){
          half8 a0 = fragLDS(bufA, lm,    q, lq);
          half8 a1 = fragLDS(bufA, 16+lm, q, lq);
          acc[0][0] = MFMA(a0, wB[0][q], acc[0][0]);
          acc[0][1] = MFMA(a1, wB[0][q], acc[0][1]);
          acc[1][0] = MFMA(a0, wB[1][q], acc[1][0]);
          acc[1][1] = MFMA(a1, wB[1][q], acc[1][1]);
        }
      }
      __syncthreads();
      #pragma unroll
      for (int ct=0; ct<2; ++ct)
        #pragma unroll
        for (int rt=0; rt<2; ++rt)
          #pragma unroll
          for (int r=0;r<4;++r)
            sGate[w*1056 + (rt*16 + lq*4 + r)*33 + ct*16 + lm] = acc[ct][rt][r];
      __syncthreads();
      {
        union { u64 uu; f16 h[4]; } hv;
        #pragma unroll
        for (int j=0;j<4;++j){
          int u = cr_u0 + j;
          float iv = sGate[0*1056 + cr_row*33 + u];
          float fv = sGate[1*1056 + cr_row*33 + u];
          float gv = sGate[2*1056 + cr_row*33 + u];
          float ov = sGate[3*1056 + cr_row*33 + u];
          float c = sigm(fv)*creg[j] + sigm(iv)*tanh_f(gv);
          creg[j] = c;
          hv.h[j] = (f16)(sigm(ov)*tanh_f(c));
        }
        f16* dst = hdst_base + (size_t)(t&7)*32*512 + cr_row*512 + b*32 + cr_u0;
        sta64(dst, hv.uu);
      }
      vmcnt0();
      __syncthreads();
      if (tid == 0) stf(&fl[b], (uint32_t)(t+1));
    }
  } else {
    // ---------------- layer-2 consumer ----------------
    half8 wA[2][16];
    half8 wB[2][16];
    #pragma unroll
    for (int ct=0; ct<2; ++ct)
      #pragma unroll
      for (int q=0;q<16;++q){
        wA[ct][q] = *(const half8*)&Wi2F[(((size_t)(nt0+ct)*16 + q)*64 + lane)*8];
        wB[ct][q] = *(const half8*)&Wh2F[(((size_t)(nt0+ct)*16 + q)*64 + lane)*8];
      }
    #pragma unroll 1
    for (int t=0; t<TSTEPS; ++t){
      if (w == 0) pollWave(fl, t+1, t);   // producers done t; consumer peers done t-1
      __syncthreads();
      float4 s0[8], s1[8];
      stageIssue(s0, h1x + ((size_t)(g*8 + (t&7))*32*512), tid);
      if (t >= 1) stageIssue(s1, h2x + ((size_t)(g*4 + ((t-1)&3))*32*512), tid);
      vmcnt0();
      stageWrite(bufA, s0, tid);
      if (t >= 1) stageWrite(bufB, s1, tid);
      __syncthreads();
      floatx4 acc[2][2];
      #pragma unroll
      for (int ct=0; ct<2; ++ct){
        acc[ct][0] = (floatx4){bs[ct],bs[ct],bs[ct],bs[ct]};
        acc[ct][1] = acc[ct][0];
      }
      #pragma unroll
      for (int q=0;q<16;++q){
        half8 a0 = fragLDS(bufA, lm,    q, lq);
        half8 a1 = fragLDS(bufA, 16+lm, q, lq);
        acc[0][0] = MFMA(a0, wA[0][q], acc[0][0]);
        acc[0][1] = MFMA(a1, wA[0][q], acc[0][1]);
        acc[1][0] = MFMA(a0, wA[1][q], acc[1][0]);
        acc[1][1] = MFMA(a1, wA[1][q], acc[1][1]);
      }
      if (t >= 1){
        #pragma unroll
        for (int q=0;q<16;++q){
          half8 a0 = fragLDS(bufB, lm,    q, lq);
          half8 a1 = fragLDS(bufB, 16+lm, q, lq);
          acc[0][0] = MFMA(a0, wB[0][q], acc[0][0]);
          acc[0][1] = MFMA(a1, wB[0][q], acc[0][1]);
          acc[1][0] = MFMA(a0, wB[1][q], acc[1][0]);
          acc[1][1] = MFMA(a1, wB[1][q], acc[1][1]);
        }
      }
      __syncthreads();
      #pragma unroll
      for (int ct=0; ct<2; ++ct)
        #pragma unroll
        for (int rt=0; rt<2; ++rt)
          #pragma unroll
          for (int r=0;r<4;++r)
            sGate[w*1056 + (rt*16 + lq*4 + r)*33 + ct*16 + lm] = acc[ct][rt][r];
      __syncthreads();
      {
        union { u64 uu; f16 h[4]; } hv;
        #pragma unroll
        for (int j=0;j<4;++j){
          int u = cr_u0 + j;
          float iv = sGate[0*1056 + cr_row*33 + u];
          float fv = sGate[1*1056 + cr_row*33 + u];
          float gv = sGate[2*1056 + cr_row*33 + u];
          float ov = sGate[3*1056 + cr_row*33 + u];
          float c = sigm(fv)*creg[j] + sigm(iv)*tanh_f(gv);
          creg[j] = c;
          hv.h[j] = (f16)(sigm(ov)*tanh_f(c));
        }
        f16* dst = hdst_base + (size_t)(t&3)*32*512 + cr_row*512 + b*32 + cr_u0;
        sta64(dst, hv.uu);
      }
      vmcnt0();
      __syncthreads();
      if (tid == 0) stf(&fl[16 + b], (uint32_t)(t+1));
    }
    // ---------- epilogue: out = h2(T-1) @ fc_w^T + fc_b ----------
    if (b == 0){
      if (w == 0) pollWave(fl, 0, TSTEPS);
      __syncthreads();
      const f16* hbase = h2x + ((size_t)(g*4 + ((TSTEPS-1)&3))*32*512);
      for (int e = tid; e < 320; e += 256){
        int row = e/10, nc = e%10;
        float s = fcb[nc];
        const float* wv = fcw + (size_t)nc*512;
        const u64* hp = (const u64*)(hbase + row*512);
        for (int k4=0;k4<128;++k4){
          union { u64 uu; f16 h[4]; } cv; cv.uu = lda64(hp + k4);
          #pragma unroll
          for (int i2=0;i2<4;++i2) s += (float)cv.h[i2]*wv[k4*4+i2];
        }
        outp[(size_t)(g*32+row)*10 + nc] = s;
      }
    }
  }
}

// ---------------- host ----------------
extern "C" void kernel_launch(void* const* d_in, const int* in_sizes, int n_in,
                              void* d_out, int out_size, void* d_ws, size_t ws_size,
                              hipStream_t stream)
{
  (void)in_sizes; (void)n_in; (void)out_size; (void)ws_size;
  const float* x = (const float*)d_in[0];
  auto F = [&](int i){ return (const float*)d_in[i]; };
  const float *Ui1=F(25), *Vi1=F(26), *Uh1=F(27), *Vh1=F(28), *bi1=F(29), *bh1=F(30);
  const float *Ui2=F(31), *Vi2=F(32), *Uh2=F(33), *Vh2=F(34), *bi2=F(35), *bh2=F(36);
  const float *fcw=F(37), *fcb=F(38);

  uint8_t* ws = (uint8_t*)d_ws;
  f16* zA   = (f16*)(ws + OFF_ZA);
  f16* zB   = (f16*)(ws + OFF_ZB);
  f16* y4x  = (f16*)(ws + OFF_Y4);
  f16* Wh1F = (f16*)(ws + OFF_WH1F);
  f16* Wi2F = (f16*)(ws + OFF_WI2F);
  f16* Wh2F = (f16*)(ws + OFF_WH2F);
  f16* Wx1F = (f16*)(ws + OFF_WX1F);
  float* bias1 = (float*)(ws + OFF_B1);
  float* bias2 = (float*)(ws + OFF_B2);
  float* stats = (float*)(ws + OFF_STATS);
  float* ab    = (float*)(ws + OFF_AB);
  f16* h1x  = (f16*)(ws + OFF_H1X);
  f16* h2x  = (f16*)(ws + OFF_H2X);
  uint32_t* flags = (uint32_t*)(ws + OFF_FLAGS);
  float* outp = (float*)d_out;

  k_zero<<<5, 256, 0, stream>>>(stats, flags);

  k_prep_W<<<dim3(32,8), 256, 0, stream>>>(Wh1F, Uh1, Vh1);
  k_prep_W<<<dim3(32,8), 256, 0, stream>>>(Wi2F, Ui2, Vi2);
  k_prep_W<<<dim3(32,8), 256, 0, stream>>>(Wh2F, Uh2, Vh2);
  k_prep_Wx<<<32, 256, 0, stream>>>(Wx1F, Ui1, Vi1);
  k_prep_bias<<<8, 256, 0, stream>>>(bias1, bi1, bh1);
  k_prep_bias<<<8, 256, 0, stream>>>(bias2, bi2, bh2);

  dim3 cgrid(5, 256);
  k_conv<<<cgrid, 256, 0, stream>>>(x, nullptr, nullptr, F(1), F(2), F(3), F(4),
                                    zA, stats + 0*64, 1024, 16);
  k_bnfin<<<1, 64, 0, stream>>>(stats + 0*64, F(5), F(6), ab + 0*64, 1.f/(256.f*1026.f));
  k_conv<<<cgrid, 256, 0, stream>>>(nullptr, zA, ab + 0*64, F(7), F(8), F(9), F(10),
                                    zB, stats + 1*64, 1026, 32);
  k_bnfin<<<1, 64, 0, stream>>>(stats + 1*64, F(11), F(12), ab + 1*64, 1.f/(256.f*1028.f));
  k_conv<<<cgrid, 256, 0, stream>>>(nullptr, zB, ab + 1*64, F(13), F(14), F(15), F(16),
                                    zA, stats + 2*64, 1028, 32);
  k_bnfin<<<1, 64, 0, stream>>>(stats + 2*64, F(17), F(18), ab + 2*64, 1.f/(256.f*1030.f));
  k_conv<<<cgrid, 256, 0, stream>>>(nullptr, zA, ab + 2*64, F(19), F(20), F(21), F(22),
                                    zB, stats + 3*64, 1030, 32);
  k_bnfin<<<1, 64, 0, stream>>>(stats + 3*64, F(23), F(24), ab + 3*64, 1.f/(256.f*1032.f));

  k_y4<<<dim3(256,5), 256, 0, stream>>>(zB, ab + 3*64, y4x);

  k_lstm<<<256, 256, 0, stream>>>(y4x,
                                  Wx1F, Wh1F, Wi2F, Wh2F,
                                  bias1, bias2,
                                  h1x, h2x, flags,
                                  fcw, fcb, outp);
}